// Round 3
// baseline (244.271 us; speedup 1.0000x reference)
//
#include <hip/hip_runtime.h>
#include <hip/hip_bf16.h>
#include <stdint.h>

#define DIN 32
#define DOUT 32
#define DE 13

typedef float f32x4 __attribute__((ext_vector_type(4)));
typedef short s16x8 __attribute__((ext_vector_type(8)));
typedef int   i32x4 __attribute__((ext_vector_type(4)));

__device__ __forceinline__ unsigned short f2bf(float f) {
    uint32_t b = __float_as_uint(f);
    b += 0x7FFFu + ((b >> 16) & 1u);
    return (unsigned short)(b >> 16);
}
__device__ __forceinline__ uint32_t pk2(float a, float b) {
    float2 t; t.x = a; t.y = b;
    __hip_bfloat162 h = __float22bfloat162_rn(t);
    return *(uint32_t*)&h;
}
__device__ __forceinline__ float sigm(float v) { return 1.f / (1.f + __expf(-v)); }
__device__ __forceinline__ float tanh_fast(float v) { return 2.f / (1.f + __expf(-2.f * v)) - 1.f; }

// ---------------------------------------------------------------------------
// kE: fused NNConv message + scatter.  msg[e] = (x[src_e] (x) [ea_e|1]) @ Wflat
// MFMA 16x16x32 bf16, weights as A (rows=o), edges as B (cols=e).
// K = 448 laid out k = d*32 + i; K-tile kt == edge-dim d.
// Lane's C values all belong to its own edge -> shuffle-free atomic scatter.
// ---------------------------------------------------------------------------
#define KE_LDS (28 * 512)
__global__ __launch_bounds__(256) void kE(const float* __restrict__ x,
        const float* __restrict__ ea, const int* __restrict__ ei,
        const float* __restrict__ nn_w, const float* __restrict__ nn_b,
        float* __restrict__ agg, float* __restrict__ cnt, int E) {
    __shared__ unsigned short Al[KE_LDS];  // 28 KB: [at2*14+kt][lane][j]
    const int tid = threadIdx.x;
    for (int t = tid; t < KE_LDS; t += 256) {
        int j = t & 7;
        int lane = (t >> 3) & 63;
        int tile = t >> 9;                 // 0..27
        int at2 = tile >= 14 ? 1 : 0;
        int kt = tile - at2 * 14;          // edge-dim d (13 = bias)
        int o = at2 * 16 + (lane & 15);    // A row m = o_local
        int i = ((lane >> 4) << 3) + j;    // A col k = i
        float v = (kt < 13) ? nn_w[(i * 32 + o) * 13 + kt] : nn_b[i * 32 + o];
        Al[t] = f2bf(v);
    }
    __syncthreads();
    const int lane = tid & 63;
    const int el = lane & 15;              // this lane's edge within strip
    const int q8 = (lane >> 4) << 3;       // i-offset for B frag
    int wave = (blockIdx.x * 256 + tid) >> 6;
    const int nw = (gridDim.x * 256) >> 6;
    const int nstrips = E >> 4;            // E % 16 == 0 (250000 = 16*15625)
    for (int s = wave; s < nstrips; s += nw) {
        const int e = (s << 4) + el;
        const int srcv = ei[e];
        const int dstv = ei[E + e];
        const float* xq = x + (size_t)srcv * 32 + q8;
        f32x4 xlo = *(const f32x4*)xq;
        f32x4 xhi = *(const f32x4*)(xq + 4);
        float xv[8] = {xlo[0], xlo[1], xlo[2], xlo[3], xhi[0], xhi[1], xhi[2], xhi[3]};
        float g[14];
        const float* eap = ea + (size_t)e * 13;
        #pragma unroll
        for (int d = 0; d < 13; ++d) g[d] = eap[d];
        g[13] = 1.0f;
        f32x4 C0 = {0.f, 0.f, 0.f, 0.f}, C1 = {0.f, 0.f, 0.f, 0.f};
        #pragma unroll
        for (int kt = 0; kt < 14; ++kt) {
            float gk = g[kt];
            i32x4 bi;
            bi[0] = pk2(xv[0] * gk, xv[1] * gk);
            bi[1] = pk2(xv[2] * gk, xv[3] * gk);
            bi[2] = pk2(xv[4] * gk, xv[5] * gk);
            bi[3] = pk2(xv[6] * gk, xv[7] * gk);
            s16x8 bfr = __builtin_bit_cast(s16x8, bi);
            s16x8 a0 = *(const s16x8*)&Al[kt * 512 + lane * 8];
            s16x8 a1 = *(const s16x8*)&Al[(14 + kt) * 512 + lane * 8];
            C0 = __builtin_amdgcn_mfma_f32_16x16x32_bf16(a0, bfr, C0, 0, 0, 0);
            C1 = __builtin_amdgcn_mfma_f32_16x16x32_bf16(a1, bfr, C1, 0, 0, 0);
        }
        // C layout: col = lane&15 = own edge, row = (lane>>4)*4 + reg = o_local
        float* ap = agg + (size_t)dstv * 32 + ((lane >> 4) << 2);
        #pragma unroll
        for (int r = 0; r < 4; ++r) atomicAdd(&ap[r], C0[r]);
        #pragma unroll
        for (int r = 0; r < 4; ++r) atomicAdd(&ap[16 + r], C1[r]);
        if (lane < 16) atomicAdd(&cnt[dstv], 1.0f);
    }
}

// ---------------------------------------------------------------------------
// kC: mean + root + celu + GRU + relu, MFMA version (unchanged from round 2).
// ---------------------------------------------------------------------------
__global__ __launch_bounds__(256) void kC(const float* __restrict__ x,
        const float* __restrict__ agg, const float* __restrict__ cnt,
        const float* __restrict__ root, const float* __restrict__ bias,
        const float* __restrict__ w_ih, const float* __restrict__ w_hh,
        const float* __restrict__ b_ih, const float* __restrict__ b_hh,
        float* __restrict__ out, float* __restrict__ hnew, int N) {
    __shared__ unsigned short Bl[14 * 64 * 8];   // 8 tiles W1, 6 tiles W2
    __shared__ unsigned short clds[4][16 * 32];  // per-wave c roundtrip
    const int tid = threadIdx.x;
    for (int t = tid; t < 14 * 64 * 8; t += 256) {
        int j = t & 7;
        int lane = (t >> 3) & 63;
        int tt = t >> 9;
        int i = ((lane >> 4) << 3) + j;
        int c = lane & 15;
        float v;
        if (tt < 8) {
            int col = tt * 16 + c;
            v = (col < 32) ? root[i * 32 + col] : w_hh[(col - 32) * 32 + i];
        } else {
            v = w_ih[((tt - 8) * 16 + c) * 32 + i];
        }
        Bl[t] = f2bf(v);
    }
    __syncthreads();
    const int lane = tid & 63;
    const int wv = tid >> 6;
    const int c15 = lane & 15;
    const int rowb = (lane >> 4) << 2;
    float binit[14];
    #pragma unroll
    for (int t = 0; t < 2; ++t) binit[t] = bias[t * 16 + c15];
    #pragma unroll
    for (int t = 2; t < 8; ++t) binit[t] = b_hh[t * 16 + c15 - 32];
    #pragma unroll
    for (int u = 0; u < 6; ++u) binit[8 + u] = b_ih[u * 16 + c15];
    int wave = (blockIdx.x * 256 + tid) >> 6;
    const int nw = (gridDim.x * 256) >> 6;
    const int nstrips = N >> 4;
    for (int s = wave; s < nstrips; s += nw) {
        const int n0 = s << 4;
        const float* xp = x + (size_t)(n0 + c15) * 32 + ((lane >> 4) << 3);
        f32x4 x0 = *(const f32x4*)xp;
        f32x4 x1 = *(const f32x4*)(xp + 4);
        s16x8 a;
        a[0] = (short)f2bf(x0[0]); a[1] = (short)f2bf(x0[1]);
        a[2] = (short)f2bf(x0[2]); a[3] = (short)f2bf(x0[3]);
        a[4] = (short)f2bf(x1[0]); a[5] = (short)f2bf(x1[1]);
        a[6] = (short)f2bf(x1[2]); a[7] = (short)f2bf(x1[3]);
        f32x4 D[8];
        #pragma unroll
        for (int t = 0; t < 8; ++t) {
            s16x8 b = *(const s16x8*)&Bl[(t * 64 + lane) * 8];
            f32x4 ci = {binit[t], binit[t], binit[t], binit[t]};
            D[t] = __builtin_amdgcn_mfma_f32_16x16x32_bf16(a, b, ci, 0, 0, 0);
        }
        float xr[4][2];
        #pragma unroll
        for (int r = 0; r < 4; ++r) {
            const int n = n0 + rowb + r;
            float cn = fmaxf(cnt[n], 1.f);
            #pragma unroll
            for (int t = 0; t < 2; ++t) {
                float ag = agg[(size_t)n * 32 + t * 16 + c15];
                xr[r][t] = x[(size_t)n * 32 + t * 16 + c15];
                float conv = ag / cn + D[t][r];
                float cv = conv > 0.f ? conv : (__expf(conv) - 1.f);  // celu
                clds[wv][(rowb + r) * 32 + t * 16 + c15] = f2bf(cv);
            }
        }
        s16x8 a2 = *(const s16x8*)&clds[wv][c15 * 32 + ((lane >> 4) << 3)];
        f32x4 G[6];
        #pragma unroll
        for (int u = 0; u < 6; ++u) {
            s16x8 b = *(const s16x8*)&Bl[((8 + u) * 64 + lane) * 8];
            f32x4 ci = {binit[8 + u], binit[8 + u], binit[8 + u], binit[8 + u]};
            G[u] = __builtin_amdgcn_mfma_f32_16x16x32_bf16(a2, b, ci, 0, 0, 0);
        }
        #pragma unroll
        for (int t = 0; t < 2; ++t) {
            #pragma unroll
            for (int r = 0; r < 4; ++r) {
                float rg = sigm(G[t][r] + D[2 + t][r]);
                float z  = sigm(G[2 + t][r] + D[4 + t][r]);
                float nn = tanh_fast(G[4 + t][r] + rg * D[6 + t][r]);
                float h  = (1.f - z) * nn + z * xr[r][t];
                float ov = h + xr[r][t];
                size_t oi = (size_t)(n0 + rowb + r) * 32 + t * 16 + c15;
                out[oi]  = ov > 0.f ? ov : 0.f;
                hnew[oi] = h;
            }
        }
    }
}

extern "C" void kernel_launch(void* const* d_in, const int* in_sizes, int n_in,
                              void* d_out, int out_size, void* d_ws, size_t ws_size,
                              hipStream_t stream) {
    const float* x    = (const float*)d_in[0];
    const float* ea   = (const float*)d_in[1];
    const float* nn_w = (const float*)d_in[2];
    const float* nn_b = (const float*)d_in[3];
    const float* root = (const float*)d_in[4];
    const float* bias = (const float*)d_in[5];
    const float* w_ih = (const float*)d_in[6];
    const float* w_hh = (const float*)d_in[7];
    const float* b_ih = (const float*)d_in[8];
    const float* b_hh = (const float*)d_in[9];
    const int*   ei   = (const int*)d_in[10];
    const int N = in_sizes[0] / DIN;
    const int E = in_sizes[10] / 2;
    float* out  = (float*)d_out;
    float* hnew = out + (size_t)N * DOUT;

    const size_t agg_bytes = (size_t)N * 32 * sizeof(float);  // 12.8 MB
    const size_t cnt_bytes = (size_t)N * sizeof(float);       // 0.4 MB

    float* agg = (float*)d_ws;
    float* cnt = (float*)((char*)d_ws + agg_bytes);
    hipMemsetAsync(agg, 0, agg_bytes + cnt_bytes, stream);
    kE<<<1024, 256, 0, stream>>>(x, ea, ei, nn_w, nn_b, agg, cnt, E);
    kC<<<512, 256, 0, stream>>>(x, agg, cnt, root, bias, w_ih, w_hh,
                                b_ih, b_hh, out, hnew, N);
}

// Round 4
// 185.176 us; speedup vs baseline: 1.3191x; 1.3191x over previous
//
#include <hip/hip_runtime.h>
#include <hip/hip_bf16.h>
#include <stdint.h>

#define DIN 32
#define DOUT 32
#define DE 13

typedef float f32x4 __attribute__((ext_vector_type(4)));
typedef short s16x8 __attribute__((ext_vector_type(8)));
typedef int   i32x4 __attribute__((ext_vector_type(4)));

__device__ __forceinline__ unsigned short f2bf(float f) {
    uint32_t b = __float_as_uint(f);
    b += 0x7FFFu + ((b >> 16) & 1u);
    return (unsigned short)(b >> 16);
}
__device__ __forceinline__ uint32_t pk2(float a, float b) {
    float2 t; t.x = a; t.y = b;
    __hip_bfloat162 h = __float22bfloat162_rn(t);
    return *(uint32_t*)&h;
}
__device__ __forceinline__ float sigm(float v) { return 1.f / (1.f + __expf(-v)); }
__device__ __forceinline__ float tanh_fast(float v) { return 2.f / (1.f + __expf(-2.f * v)) - 1.f; }

// ---------------------------------------------------------------------------
// kE: fused NNConv message + scatter.  msg[e] = (x[src_e] (x) [ea_e|1]) @ Wflat
// MFMA 16x16x32 bf16, weights as A (rows=o), edges as B (cols).
// After MFMA: LDS transpose (wave-private) so the atomic scatter is lane=o,
// one contiguous 128B agg row per edge (kB-style coalescing; round-2 evidence
// WRITE=39MB vs round-3's per-lane scatter at 132.8MB).
// ---------------------------------------------------------------------------
#define KE_LDS (28 * 512)
__global__ __launch_bounds__(256) void kE(const float* __restrict__ x,
        const float* __restrict__ ea, const int* __restrict__ ei,
        const float* __restrict__ nn_w, const float* __restrict__ nn_b,
        float* __restrict__ agg, float* __restrict__ cnt, int E) {
    __shared__ unsigned short Al[KE_LDS];    // 28 KB: [at2*14+kt][lane][j]
    __shared__ float tr[4][16 * 36];         // per-wave transpose buffer (9 KB)
    const int tid = threadIdx.x;
    for (int t = tid; t < KE_LDS; t += 256) {
        int j = t & 7;
        int lane = (t >> 3) & 63;
        int tile = t >> 9;                 // 0..27
        int at2 = tile >= 14 ? 1 : 0;
        int kt = tile - at2 * 14;          // edge-dim d (13 = bias)
        int o = at2 * 16 + (lane & 15);    // A row m = o_local
        int i = ((lane >> 4) << 3) + j;    // A col k = i
        float v = (kt < 13) ? nn_w[(i * 32 + o) * 13 + kt] : nn_b[i * 32 + o];
        Al[t] = f2bf(v);
    }
    __syncthreads();
    const int lane = tid & 63;
    const int wv = tid >> 6;
    const int el = lane & 15;              // this lane's edge within strip
    const int o31 = lane & 31;
    const int q8 = (lane >> 4) << 3;       // i-offset for B frag
    const int rowb = (lane >> 4) << 2;
    float* trw = &tr[wv][0];
    int wave = (blockIdx.x * 256 + tid) >> 6;
    const int nw = (gridDim.x * 256) >> 6;
    const int nstrips = E >> 4;            // E % 16 == 0 (250000 = 16*15625)
    for (int s = wave; s < nstrips; s += nw) {
        const int e = (s << 4) + el;
        const int dstv = ei[E + e];
        const int srcv = ei[e];
        const float* xq = x + (size_t)srcv * 32 + q8;
        f32x4 xlo = *(const f32x4*)xq;
        f32x4 xhi = *(const f32x4*)(xq + 4);
        float xv[8] = {xlo[0], xlo[1], xlo[2], xlo[3], xhi[0], xhi[1], xhi[2], xhi[3]};
        float g[14];
        const float* eap = ea + (size_t)e * 13;
        #pragma unroll
        for (int d = 0; d < 13; ++d) g[d] = eap[d];
        g[13] = 1.0f;
        f32x4 C0 = {0.f, 0.f, 0.f, 0.f}, C1 = {0.f, 0.f, 0.f, 0.f};
        #pragma unroll
        for (int kt = 0; kt < 14; ++kt) {
            float gk = g[kt];
            i32x4 bi;
            bi[0] = pk2(xv[0] * gk, xv[1] * gk);
            bi[1] = pk2(xv[2] * gk, xv[3] * gk);
            bi[2] = pk2(xv[4] * gk, xv[5] * gk);
            bi[3] = pk2(xv[6] * gk, xv[7] * gk);
            s16x8 bfr = __builtin_bit_cast(s16x8, bi);
            s16x8 a0 = *(const s16x8*)&Al[kt * 512 + lane * 8];
            s16x8 a1 = *(const s16x8*)&Al[(14 + kt) * 512 + lane * 8];
            C0 = __builtin_amdgcn_mfma_f32_16x16x32_bf16(a0, bfr, C0, 0, 0, 0);
            C1 = __builtin_amdgcn_mfma_f32_16x16x32_bf16(a1, bfr, C1, 0, 0, 0);
        }
        // C layout: col = el (edge), row = rowb+r (o_local). Transpose via LDS.
        *(f32x4*)&trw[el * 36 + rowb] = C0;
        *(f32x4*)&trw[el * 36 + 16 + rowb] = C1;
        // 8 coalesced atomic passes: wave covers 2 edges/pass, lane = o.
        #pragma unroll
        for (int p = 0; p < 8; ++p) {
            int e2 = (p << 1) + (lane >> 5);
            float v = trw[e2 * 36 + o31];
            int d2 = __shfl(dstv, e2, 64);
            atomicAdd(&agg[(size_t)d2 * 32 + o31], v);
        }
        if (lane < 16) atomicAdd(&cnt[dstv], 1.0f);
    }
}

// ---------------------------------------------------------------------------
// kC: mean + root + celu + GRU + relu, MFMA version.
// ---------------------------------------------------------------------------
__global__ __launch_bounds__(256) void kC(const float* __restrict__ x,
        const float* __restrict__ agg, const float* __restrict__ cnt,
        const float* __restrict__ root, const float* __restrict__ bias,
        const float* __restrict__ w_ih, const float* __restrict__ w_hh,
        const float* __restrict__ b_ih, const float* __restrict__ b_hh,
        float* __restrict__ out, float* __restrict__ hnew, int N) {
    __shared__ unsigned short Bl[14 * 64 * 8];   // 8 tiles W1, 6 tiles W2
    __shared__ unsigned short clds[4][16 * 32];  // per-wave c roundtrip
    const int tid = threadIdx.x;
    for (int t = tid; t < 14 * 64 * 8; t += 256) {
        int j = t & 7;
        int lane = (t >> 3) & 63;
        int tt = t >> 9;
        int i = ((lane >> 4) << 3) + j;
        int c = lane & 15;
        float v;
        if (tt < 8) {
            int col = tt * 16 + c;
            v = (col < 32) ? root[i * 32 + col] : w_hh[(col - 32) * 32 + i];
        } else {
            v = w_ih[((tt - 8) * 16 + c) * 32 + i];
        }
        Bl[t] = f2bf(v);
    }
    __syncthreads();
    const int lane = tid & 63;
    const int wv = tid >> 6;
    const int c15 = lane & 15;
    const int rowb = (lane >> 4) << 2;
    float binit[14];
    #pragma unroll
    for (int t = 0; t < 2; ++t) binit[t] = bias[t * 16 + c15];
    #pragma unroll
    for (int t = 2; t < 8; ++t) binit[t] = b_hh[t * 16 + c15 - 32];
    #pragma unroll
    for (int u = 0; u < 6; ++u) binit[8 + u] = b_ih[u * 16 + c15];
    int wave = (blockIdx.x * 256 + tid) >> 6;
    const int nw = (gridDim.x * 256) >> 6;
    const int nstrips = N >> 4;
    for (int s = wave; s < nstrips; s += nw) {
        const int n0 = s << 4;
        const float* xp = x + (size_t)(n0 + c15) * 32 + ((lane >> 4) << 3);
        f32x4 x0 = *(const f32x4*)xp;
        f32x4 x1 = *(const f32x4*)(xp + 4);
        s16x8 a;
        a[0] = (short)f2bf(x0[0]); a[1] = (short)f2bf(x0[1]);
        a[2] = (short)f2bf(x0[2]); a[3] = (short)f2bf(x0[3]);
        a[4] = (short)f2bf(x1[0]); a[5] = (short)f2bf(x1[1]);
        a[6] = (short)f2bf(x1[2]); a[7] = (short)f2bf(x1[3]);
        f32x4 D[8];
        #pragma unroll
        for (int t = 0; t < 8; ++t) {
            s16x8 b = *(const s16x8*)&Bl[(t * 64 + lane) * 8];
            f32x4 ci = {binit[t], binit[t], binit[t], binit[t]};
            D[t] = __builtin_amdgcn_mfma_f32_16x16x32_bf16(a, b, ci, 0, 0, 0);
        }
        float xr[4][2];
        #pragma unroll
        for (int r = 0; r < 4; ++r) {
            const int n = n0 + rowb + r;
            float cn = fmaxf(cnt[n], 1.f);
            #pragma unroll
            for (int t = 0; t < 2; ++t) {
                float ag = agg[(size_t)n * 32 + t * 16 + c15];
                xr[r][t] = x[(size_t)n * 32 + t * 16 + c15];
                float conv = ag / cn + D[t][r];
                float cv = conv > 0.f ? conv : (__expf(conv) - 1.f);  // celu
                clds[wv][(rowb + r) * 32 + t * 16 + c15] = f2bf(cv);
            }
        }
        s16x8 a2 = *(const s16x8*)&clds[wv][c15 * 32 + ((lane >> 4) << 3)];
        f32x4 G[6];
        #pragma unroll
        for (int u = 0; u < 6; ++u) {
            s16x8 b = *(const s16x8*)&Bl[((8 + u) * 64 + lane) * 8];
            f32x4 ci = {binit[8 + u], binit[8 + u], binit[8 + u], binit[8 + u]};
            G[u] = __builtin_amdgcn_mfma_f32_16x16x32_bf16(a2, b, ci, 0, 0, 0);
        }
        #pragma unroll
        for (int t = 0; t < 2; ++t) {
            #pragma unroll
            for (int r = 0; r < 4; ++r) {
                float rg = sigm(G[t][r] + D[2 + t][r]);
                float z  = sigm(G[2 + t][r] + D[4 + t][r]);
                float nn = tanh_fast(G[4 + t][r] + rg * D[6 + t][r]);
                float h  = (1.f - z) * nn + z * xr[r][t];
                float ov = h + xr[r][t];
                size_t oi = (size_t)(n0 + rowb + r) * 32 + t * 16 + c15;
                out[oi]  = ov > 0.f ? ov : 0.f;
                hnew[oi] = h;
            }
        }
    }
}

extern "C" void kernel_launch(void* const* d_in, const int* in_sizes, int n_in,
                              void* d_out, int out_size, void* d_ws, size_t ws_size,
                              hipStream_t stream) {
    const float* x    = (const float*)d_in[0];
    const float* ea   = (const float*)d_in[1];
    const float* nn_w = (const float*)d_in[2];
    const float* nn_b = (const float*)d_in[3];
    const float* root = (const float*)d_in[4];
    const float* bias = (const float*)d_in[5];
    const float* w_ih = (const float*)d_in[6];
    const float* w_hh = (const float*)d_in[7];
    const float* b_ih = (const float*)d_in[8];
    const float* b_hh = (const float*)d_in[9];
    const int*   ei   = (const int*)d_in[10];
    const int N = in_sizes[0] / DIN;
    const int E = in_sizes[10] / 2;
    float* out  = (float*)d_out;
    float* hnew = out + (size_t)N * DOUT;

    const size_t agg_bytes = (size_t)N * 32 * sizeof(float);  // 12.8 MB
    const size_t cnt_bytes = (size_t)N * sizeof(float);       // 0.4 MB

    float* agg = (float*)d_ws;
    float* cnt = (float*)((char*)d_ws + agg_bytes);
    hipMemsetAsync(agg, 0, agg_bytes + cnt_bytes, stream);
    kE<<<2048, 256, 0, stream>>>(x, ea, ei, nn_w, nn_b, agg, cnt, E);
    kC<<<1568, 256, 0, stream>>>(x, agg, cnt, root, bias, w_ih, w_hh,
                                 b_ih, b_hh, out, hnew, N);
}

// Round 5
// 164.629 us; speedup vs baseline: 1.4838x; 1.1248x over previous
//
#include <hip/hip_runtime.h>
#include <hip/hip_bf16.h>
#include <stdint.h>

#define DIN 32
#define DOUT 32
#define DE 13

typedef float f32x4 __attribute__((ext_vector_type(4)));
typedef short s16x8 __attribute__((ext_vector_type(8)));
typedef int   i32x4 __attribute__((ext_vector_type(4)));

__device__ __forceinline__ unsigned short f2bf(float f) {
    uint32_t b = __float_as_uint(f);
    b += 0x7FFFu + ((b >> 16) & 1u);
    return (unsigned short)(b >> 16);
}
__device__ __forceinline__ uint32_t pk2(float a, float b) {
    float2 t; t.x = a; t.y = b;
    __hip_bfloat162 h = __float22bfloat162_rn(t);
    return *(uint32_t*)&h;
}
__device__ __forceinline__ float sigm(float v) { return 1.f / (1.f + __expf(-v)); }
__device__ __forceinline__ float tanh_fast(float v) { return 2.f / (1.f + __expf(-2.f * v)) - 1.f; }

// ---------------------------------------------------------------------------
// kE: fused NNConv message + scatter.  msg[e] = (x[src_e] (x) [ea_e|1]) @ Wflat
// MFMA 16x16x32 bf16, weights as A (rows=o), edges as B (cols).
// Post-MFMA LDS transpose -> packed-bf16 atomics (global_atomic_pk_add_bf16):
// 4M atomic ops (was 8M fp32), 1 line per edge row (was 2).
// ---------------------------------------------------------------------------
#define KE_LDS (28 * 512)
__global__ __launch_bounds__(256) void kE(const float* __restrict__ x,
        const float* __restrict__ ea, const int* __restrict__ ei,
        const float* __restrict__ nn_w, const float* __restrict__ nn_b,
        __hip_bfloat162* __restrict__ agg, float* __restrict__ cnt, int E) {
    __shared__ unsigned short Al[KE_LDS];    // 28 KB: [at2*14+kt][lane][j]
    __shared__ float tr[4][16 * 36];         // per-wave ea-stage + transpose buffer
    const int tid = threadIdx.x;
    for (int t = tid; t < KE_LDS; t += 256) {
        int j = t & 7;
        int lane = (t >> 3) & 63;
        int tile = t >> 9;                 // 0..27
        int at2 = tile >= 14 ? 1 : 0;
        int kt = tile - at2 * 14;          // edge-dim d (13 = bias)
        int o = at2 * 16 + (lane & 15);    // A row m = o_local
        int i = ((lane >> 4) << 3) + j;    // A col k = i
        float v = (kt < 13) ? nn_w[(i * 32 + o) * 13 + kt] : nn_b[i * 32 + o];
        Al[t] = f2bf(v);
    }
    __syncthreads();
    const int lane = tid & 63;
    const int wv = tid >> 6;
    const int el = lane & 15;              // this lane's edge within strip
    const int q8 = (lane >> 4) << 3;       // i-offset for B frag
    const int rowb = (lane >> 4) << 2;
    const int pe = lane >> 4;              // 0..3 (edge-quad for scatter)
    const int c2 = lane & 15;              // col-pair for scatter
    float* trw = &tr[wv][0];
    int wave = (blockIdx.x * 256 + tid) >> 6;
    const int nw = (gridDim.x * 256) >> 6;
    const int nstrips = E >> 4;            // E % 16 == 0 (250000 = 16*15625)
    for (int s = wave; s < nstrips; s += nw) {
        const int e = (s << 4) + el;
        const int dstv = ei[E + e];
        const int srcv = ei[e];
        // coalesced ea stage: 16 edges x 13 floats = 208 floats
        const float* eab = ea + (size_t)(s << 4) * 13;
        #pragma unroll
        for (int t = 0; t < 4; ++t) {
            int idx = t * 64 + lane;
            if (idx < 208) trw[idx] = eab[idx];
        }
        const float* xq = x + (size_t)srcv * 32 + q8;
        f32x4 xlo = *(const f32x4*)xq;
        f32x4 xhi = *(const f32x4*)(xq + 4);
        float xv[8] = {xlo[0], xlo[1], xlo[2], xlo[3], xhi[0], xhi[1], xhi[2], xhi[3]};
        float g[14];
        #pragma unroll
        for (int d = 0; d < 13; ++d) g[d] = trw[el * 13 + d];
        g[13] = 1.0f;
        f32x4 C0 = {0.f, 0.f, 0.f, 0.f}, C1 = {0.f, 0.f, 0.f, 0.f};
        #pragma unroll
        for (int kt = 0; kt < 14; ++kt) {
            float gk = g[kt];
            i32x4 bi;
            bi[0] = pk2(xv[0] * gk, xv[1] * gk);
            bi[1] = pk2(xv[2] * gk, xv[3] * gk);
            bi[2] = pk2(xv[4] * gk, xv[5] * gk);
            bi[3] = pk2(xv[6] * gk, xv[7] * gk);
            s16x8 bfr = __builtin_bit_cast(s16x8, bi);
            s16x8 a0 = *(const s16x8*)&Al[kt * 512 + lane * 8];
            s16x8 a1 = *(const s16x8*)&Al[(14 + kt) * 512 + lane * 8];
            C0 = __builtin_amdgcn_mfma_f32_16x16x32_bf16(a0, bfr, C0, 0, 0, 0);
            C1 = __builtin_amdgcn_mfma_f32_16x16x32_bf16(a1, bfr, C1, 0, 0, 0);
        }
        // C layout: col = el (edge), row = rowb+r (o_local). Transpose via LDS.
        *(f32x4*)&trw[el * 36 + rowb] = C0;
        *(f32x4*)&trw[el * 36 + 16 + rowb] = C1;
        // 4 packed-bf16 atomic passes: wave covers 4 edges/pass, lane = col pair.
        #pragma unroll
        for (int p = 0; p < 4; ++p) {
            int e4 = (p << 2) + pe;
            float v0 = trw[e4 * 36 + 2 * c2];
            float v1 = trw[e4 * 36 + 2 * c2 + 1];
            int d4 = __shfl(dstv, e4, 64);
            float2 fv; fv.x = v0; fv.y = v1;
            __hip_bfloat162 val = __float22bfloat162_rn(fv);
            unsafeAtomicAdd(&agg[(size_t)d4 * 16 + c2], val);
        }
        if (lane < 16) atomicAdd(&cnt[dstv], 1.0f);
    }
}

// ---------------------------------------------------------------------------
// kC: mean + root + celu + GRU + relu, MFMA version. agg is bf16 now.
// ---------------------------------------------------------------------------
__global__ __launch_bounds__(256) void kC(const float* __restrict__ x,
        const __hip_bfloat16* __restrict__ aggb, const float* __restrict__ cnt,
        const float* __restrict__ root, const float* __restrict__ bias,
        const float* __restrict__ w_ih, const float* __restrict__ w_hh,
        const float* __restrict__ b_ih, const float* __restrict__ b_hh,
        float* __restrict__ out, float* __restrict__ hnew, int N) {
    __shared__ unsigned short Bl[14 * 64 * 8];   // 8 tiles W1, 6 tiles W2
    __shared__ unsigned short clds[4][16 * 32];  // per-wave c roundtrip
    const int tid = threadIdx.x;
    for (int t = tid; t < 14 * 64 * 8; t += 256) {
        int j = t & 7;
        int lane = (t >> 3) & 63;
        int tt = t >> 9;
        int i = ((lane >> 4) << 3) + j;
        int c = lane & 15;
        float v;
        if (tt < 8) {
            int col = tt * 16 + c;
            v = (col < 32) ? root[i * 32 + col] : w_hh[(col - 32) * 32 + i];
        } else {
            v = w_ih[((tt - 8) * 16 + c) * 32 + i];
        }
        Bl[t] = f2bf(v);
    }
    __syncthreads();
    const int lane = tid & 63;
    const int wv = tid >> 6;
    const int c15 = lane & 15;
    const int rowb = (lane >> 4) << 2;
    float binit[14];
    #pragma unroll
    for (int t = 0; t < 2; ++t) binit[t] = bias[t * 16 + c15];
    #pragma unroll
    for (int t = 2; t < 8; ++t) binit[t] = b_hh[t * 16 + c15 - 32];
    #pragma unroll
    for (int u = 0; u < 6; ++u) binit[8 + u] = b_ih[u * 16 + c15];
    int wave = (blockIdx.x * 256 + tid) >> 6;
    const int nw = (gridDim.x * 256) >> 6;
    const int nstrips = N >> 4;
    for (int s = wave; s < nstrips; s += nw) {
        const int n0 = s << 4;
        const float* xp = x + (size_t)(n0 + c15) * 32 + ((lane >> 4) << 3);
        f32x4 x0 = *(const f32x4*)xp;
        f32x4 x1 = *(const f32x4*)(xp + 4);
        s16x8 a;
        a[0] = (short)f2bf(x0[0]); a[1] = (short)f2bf(x0[1]);
        a[2] = (short)f2bf(x0[2]); a[3] = (short)f2bf(x0[3]);
        a[4] = (short)f2bf(x1[0]); a[5] = (short)f2bf(x1[1]);
        a[6] = (short)f2bf(x1[2]); a[7] = (short)f2bf(x1[3]);
        f32x4 D[8];
        #pragma unroll
        for (int t = 0; t < 8; ++t) {
            s16x8 b = *(const s16x8*)&Bl[(t * 64 + lane) * 8];
            f32x4 ci = {binit[t], binit[t], binit[t], binit[t]};
            D[t] = __builtin_amdgcn_mfma_f32_16x16x32_bf16(a, b, ci, 0, 0, 0);
        }
        float xr[4][2];
        #pragma unroll
        for (int r = 0; r < 4; ++r) {
            const int n = n0 + rowb + r;
            float cn = fmaxf(cnt[n], 1.f);
            #pragma unroll
            for (int t = 0; t < 2; ++t) {
                float ag = __bfloat162float(aggb[(size_t)n * 32 + t * 16 + c15]);
                xr[r][t] = x[(size_t)n * 32 + t * 16 + c15];
                float conv = ag / cn + D[t][r];
                float cv = conv > 0.f ? conv : (__expf(conv) - 1.f);  // celu
                clds[wv][(rowb + r) * 32 + t * 16 + c15] = f2bf(cv);
            }
        }
        s16x8 a2 = *(const s16x8*)&clds[wv][c15 * 32 + ((lane >> 4) << 3)];
        f32x4 G[6];
        #pragma unroll
        for (int u = 0; u < 6; ++u) {
            s16x8 b = *(const s16x8*)&Bl[((8 + u) * 64 + lane) * 8];
            f32x4 ci = {binit[8 + u], binit[8 + u], binit[8 + u], binit[8 + u]};
            G[u] = __builtin_amdgcn_mfma_f32_16x16x32_bf16(a2, b, ci, 0, 0, 0);
        }
        #pragma unroll
        for (int t = 0; t < 2; ++t) {
            #pragma unroll
            for (int r = 0; r < 4; ++r) {
                float rg = sigm(G[t][r] + D[2 + t][r]);
                float z  = sigm(G[2 + t][r] + D[4 + t][r]);
                float nn = tanh_fast(G[4 + t][r] + rg * D[6 + t][r]);
                float h  = (1.f - z) * nn + z * xr[r][t];
                float ov = h + xr[r][t];
                size_t oi = (size_t)(n0 + rowb + r) * 32 + t * 16 + c15;
                out[oi]  = ov > 0.f ? ov : 0.f;
                hnew[oi] = h;
            }
        }
    }
}

extern "C" void kernel_launch(void* const* d_in, const int* in_sizes, int n_in,
                              void* d_out, int out_size, void* d_ws, size_t ws_size,
                              hipStream_t stream) {
    const float* x    = (const float*)d_in[0];
    const float* ea   = (const float*)d_in[1];
    const float* nn_w = (const float*)d_in[2];
    const float* nn_b = (const float*)d_in[3];
    const float* root = (const float*)d_in[4];
    const float* bias = (const float*)d_in[5];
    const float* w_ih = (const float*)d_in[6];
    const float* w_hh = (const float*)d_in[7];
    const float* b_ih = (const float*)d_in[8];
    const float* b_hh = (const float*)d_in[9];
    const int*   ei   = (const int*)d_in[10];
    const int N = in_sizes[0] / DIN;
    const int E = in_sizes[10] / 2;
    float* out  = (float*)d_out;
    float* hnew = out + (size_t)N * DOUT;

    const size_t agg_bytes = (size_t)N * 32 * sizeof(__hip_bfloat16);  // 6.4 MB
    const size_t cnt_bytes = (size_t)N * sizeof(float);                // 0.4 MB

    __hip_bfloat162* agg = (__hip_bfloat162*)d_ws;
    float* cnt = (float*)((char*)d_ws + agg_bytes);
    hipMemsetAsync(d_ws, 0, agg_bytes + cnt_bytes, stream);
    kE<<<2048, 256, 0, stream>>>(x, ea, ei, nn_w, nn_b, agg, cnt, E);
    kC<<<512, 256, 0, stream>>>(x, (const __hip_bfloat16*)d_ws, cnt, root, bias,
                                w_ih, w_hh, b_ih, b_hh, out, hnew, N);
}